// Round 9
// baseline (485.049 us; speedup 1.0000x reference)
//
#include <hip/hip_runtime.h>

#define HH 4
#define FF 128
#define DD 32

typedef float f32x4 __attribute__((ext_vector_type(4)));

// ---------------- scatter (sort) ----------------

__global__ void scatter_kernel(const int* __restrict__ src, const int* __restrict__ dst,
                               int* __restrict__ cursor, int2* __restrict__ ed, int E) {
    int i = blockIdx.x * blockDim.x + threadIdx.x;
    if (i >= E) return;
    int s = src[i];
    int pos = atomicAdd(&cursor[s], 1);
    long long pack = (unsigned)i | ((long long)dst[i] << 32);   // .x=i, .y=dst (LE)
    __builtin_nontemporal_store(pack, (long long*)&ed[pos]);
}

// ---------------- fused: qk projection + histogram ----------------

__global__ __launch_bounds__(256) void qk_hist_kernel(
    const float* __restrict__ feat, const float* __restrict__ wq,
    const float* __restrict__ wk, float* __restrict__ q,
    float* __restrict__ k, int N,
    const int* __restrict__ src, int* __restrict__ counts, int E, int QKB) {
    __shared__ float fs[32 * FF];
    int bid = blockIdx.x;
    if (bid >= QKB) {           // ---- histogram role ----
        int i = ((bid - QKB) * 256 + threadIdx.x) * 4;
        if (i + 3 < E) {
            int4 v = *(const int4*)(src + i);
            atomicAdd(&counts[v.x], 1);
            atomicAdd(&counts[v.y], 1);
            atomicAdd(&counts[v.z], 1);
            atomicAdd(&counts[v.w], 1);
        } else {
            for (; i < E; ++i) atomicAdd(&counts[src[i]], 1);
        }
        return;
    }
    // ---- qk role ----
    int n0 = bid * 32;
    int nb = N - n0; if (nb > 32) nb = 32;
    const float4* s4 = (const float4*)(feat + (size_t)n0 * FF);
    int nf4 = nb * FF / 4;
    for (int i = threadIdx.x; i < nf4; i += 256) ((float4*)fs)[i] = s4[i];
    __syncthreads();

    int isK = threadIdx.x >> 7;
    int o   = threadIdx.x & 127;
    int h = o >> 5, d = o & 31;
    const float* w = (isK ? wk : wq) + ((size_t)h * FF) * DD + d;

    float acc[32];
#pragma unroll
    for (int e = 0; e < 32; ++e) acc[e] = 0.f;
    for (int f = 0; f < FF; f += 4) {
        float w0 = w[(f + 0) * DD], w1 = w[(f + 1) * DD];
        float w2 = w[(f + 2) * DD], w3 = w[(f + 3) * DD];
#pragma unroll
        for (int e = 0; e < 32; ++e) {
            float4 fv = *(const float4*)&fs[e * FF + f];
            acc[e] += fv.x * w0 + fv.y * w1 + fv.z * w2 + fv.w * w3;
        }
    }
    float* outp = isK ? k : q;
    for (int e = 0; e < nb; ++e)
        outp[((size_t)(n0 + e) * HH + h) * DD + d] = acc[e];
}

// ---------------- fused: kk projection + group-offset alloc ----------------

__global__ __launch_bounds__(256) void kk_alloc_kernel(
    const float* __restrict__ kbuf, const float* __restrict__ wk,
    float* __restrict__ kkout, int N,
    const int* __restrict__ counts, int* __restrict__ startb,
    int* __restrict__ cursor, int* __restrict__ gcur, int KKB) {
    __shared__ float ks[16 * FF];
    int bid = blockIdx.x;
    if (bid >= KKB) {           // ---- alloc role: wave scan + one atomic ----
        int sid = (bid - KKB) * 256 + threadIdx.x;
        int lane = threadIdx.x & 63;
        int cnt = (sid < N) ? counts[sid] : 0;
        int incl = cnt;
#pragma unroll
        for (int off = 1; off < 64; off <<= 1) {
            int y = __shfl_up(incl, off, 64);
            if (lane >= off) incl += y;
        }
        int total = __shfl(incl, 63, 64);
        int base = 0;
        if (lane == 63) base = atomicAdd(gcur, total);
        base = __shfl(base, 63, 64);
        if (sid < N) {
            int st = base + incl - cnt;
            startb[sid] = st;
            cursor[sid] = st;
        }
        return;
    }
    // ---- kk role ----
    int n0 = bid * 16;
    int nb = N - n0; if (nb > 16) nb = 16;
    const float4* s4 = (const float4*)(kbuf + (size_t)n0 * FF);
    int nf4 = nb * FF / 4;
    for (int i = threadIdx.x; i < nf4; i += 256) ((float4*)ks)[i] = s4[i];
    __syncthreads();

    int o = threadIdx.x;
    int h1 = o >> 7, f1 = o & 127;
    int h2 = h1 + 2;
    const float* w1 = wk + ((size_t)h1 * FF + f1) * DD;
    const float* w2 = wk + ((size_t)h2 * FF + f1) * DD;

    float acc1[16], acc2[16];
#pragma unroll
    for (int e = 0; e < 16; ++e) { acc1[e] = 0.f; acc2[e] = 0.f; }
    for (int d = 0; d < DD; d += 4) {
        float4 wv1 = *(const float4*)&w1[d];
        float4 wv2 = *(const float4*)&w2[d];
#pragma unroll
        for (int e = 0; e < 16; ++e) {
            float4 k1 = *(const float4*)&ks[e * FF + h1 * DD + d];
            float4 k2 = *(const float4*)&ks[e * FF + h2 * DD + d];
            acc1[e] += k1.x * wv1.x + k1.y * wv1.y + k1.z * wv1.z + k1.w * wv1.w;
            acc2[e] += k2.x * wv2.x + k2.y * wv2.y + k2.z * wv2.z + k2.w * wv2.w;
        }
    }
    for (int e = 0; e < nb; ++e) {
        kkout[((size_t)(n0 + e) * HH + h1) * FF + f1] = acc1[e];
        kkout[((size_t)(n0 + e) * HH + h2) * FF + f1] = acc2[e];
    }
}

// ---------------- group kernel v9: 8-lane edge groups, 8 edges/step ----------------
// Lane u (= lane&7) covers rel/kk f-slice [u*16, u*16+16) and q/k d-slice
// [u*4, u*4+4) per head. 4-shfl butterfly lands head hsel = 2*(u&1)+((u&2)>>1)
// on lane u (mod 4) -- same layout as v8's epilogue.

__device__ __forceinline__ float dot4(f32x4 a, f32x4 b) {
    return a.x * b.x + a.y * b.y + a.z * b.z + a.w * b.w;
}

__device__ __forceinline__ int score4(         // slow-path helper (16-lane form)
    const float* __restrict__ rel, const float* __restrict__ k,
    int pv, int dv, int j0, int g, int t,
    const float4* kkA, const float4* kkB, const float2* qv,
    float* ev, int* e_i_out) {
    int idx = j0 + g;
    int e_i = __shfl(pv, idx, 64);
    int dd  = __shfl(dv, idx, 64);
    *e_i_out = e_i;
    const float* rp = rel + (size_t)e_i * FF + t * 8;
    f32x4 r0 = __builtin_nontemporal_load((const f32x4*)rp);
    f32x4 r1 = __builtin_nontemporal_load((const f32x4*)(rp + 4));
#pragma unroll
    for (int h = 0; h < HH; ++h) {
        float2 kv = *(const float2*)(k + ((size_t)dd * HH + h) * DD + t * 2);
        float a = r0.x * kkA[h].x + r0.y * kkA[h].y + r0.z * kkA[h].z + r0.w * kkA[h].w
                + r1.x * kkB[h].x + r1.y * kkB[h].y + r1.z * kkB[h].z + r1.w * kkB[h].w
                + qv[h].x * kv.x + qv[h].y * kv.y;
#pragma unroll
        for (int off = 1; off < 16; off <<= 1) a += __shfl_xor(a, off, 64);
        ev[h] = a >= 0.f ? a : 0.01f * a;
    }
    return idx;
}

__global__ __launch_bounds__(64) void group_kernel(
    const float* __restrict__ rel, const int2* __restrict__ ed,
    const float* __restrict__ q, const float* __restrict__ k,
    const float* __restrict__ kk, const int* __restrict__ start,
    const int* __restrict__ counts, float* __restrict__ out, int N) {
    __shared__ __align__(16) float e_buf[128][4];
    int s = blockIdx.x;
    if (s >= N) return;
    int cnt = counts[s];
    if (cnt == 0) return;
    int base = start[s];
    int lane = threadIdx.x;
    int u = lane & 7;            // position within 8-lane group
    int gg = lane >> 3;          // edge-group 0..7
    int hsel = ((u & 1) << 1) | ((u & 2) >> 1);

    // per-lane fragments: kk f-slice (16 floats x 4 heads), q d-slice (4 x 4 heads)
    f32x4 kkv[16];
    f32x4 qq[HH];
    {
        const float* kkb = kk + (size_t)s * (HH * FF) + u * 16;
        const float* qb  = q  + (size_t)s * (HH * DD) + u * 4;
#pragma unroll
        for (int h = 0; h < HH; ++h) {
#pragma unroll
            for (int j = 0; j < 4; ++j)
                kkv[h * 4 + j] = *(const f32x4*)(kkb + h * FF + j * 4);
            qq[h] = *(const f32x4*)(qb + h * DD);
        }
    }

    float mloc = -INFINITY;
    bool fast = (cnt <= 128);

    for (int c0 = 0; c0 < cnt; c0 += 64) {
        int nc = min(cnt - c0, 64);
        int pv = 0, dv = 0;
        if (lane < nc) { int2 pd = ed[base + c0 + lane]; pv = pd.x; dv = pd.y; }
        for (int j0 = 0; j0 < nc; j0 += 8) {
            int idx = j0 + gg;
            int sel = idx < nc ? idx : 0;
            int e_i = __shfl(pv, sel, 64);
            int dd  = __shfl(dv, sel, 64);
            const float* rp = rel + (size_t)e_i * FF + u * 16;
            f32x4 r0 = __builtin_nontemporal_load((const f32x4*)rp);
            f32x4 r1 = __builtin_nontemporal_load((const f32x4*)(rp + 4));
            f32x4 r2 = __builtin_nontemporal_load((const f32x4*)(rp + 8));
            f32x4 r3 = __builtin_nontemporal_load((const f32x4*)(rp + 12));
            const float* kp = k + (size_t)dd * (HH * DD) + u * 4;
            f32x4 kv0 = *(const f32x4*)(kp);
            f32x4 kv1 = *(const f32x4*)(kp + DD);
            f32x4 kv2 = *(const f32x4*)(kp + 2 * DD);
            f32x4 kv3 = *(const f32x4*)(kp + 3 * DD);

            float p[HH];
            p[0] = dot4(r0, kkv[0])  + dot4(r1, kkv[1])  + dot4(r2, kkv[2])  + dot4(r3, kkv[3])  + dot4(kv0, qq[0]);
            p[1] = dot4(r0, kkv[4])  + dot4(r1, kkv[5])  + dot4(r2, kkv[6])  + dot4(r3, kkv[7])  + dot4(kv1, qq[1]);
            p[2] = dot4(r0, kkv[8])  + dot4(r1, kkv[9])  + dot4(r2, kkv[10]) + dot4(r3, kkv[11]) + dot4(kv2, qq[2]);
            p[3] = dot4(r0, kkv[12]) + dot4(r1, kkv[13]) + dot4(r2, kkv[14]) + dot4(r3, kkv[15]) + dot4(kv3, qq[3]);

            // 4-shfl head-specializing butterfly over the 8-lane group
            float sx = (u & 1) ? p[0] : p[2];
            float sy = (u & 1) ? p[1] : p[3];
            float rx = __shfl_xor(sx, 1, 64);
            float ry = __shfl_xor(sy, 1, 64);
            float a0 = ((u & 1) ? p[2] : p[0]) + rx;
            float a1 = ((u & 1) ? p[3] : p[1]) + ry;
            float sz = (u & 2) ? a0 : a1;
            float rz = __shfl_xor(sz, 2, 64);
            float e = ((u & 2) ? a1 : a0) + rz;        // head hsel, 4-lane sum
            e += __shfl_xor(e, 4, 64);                 // full 8-lane sum
            e = e >= 0.f ? e : 0.01f * e;              // leaky_relu(0.01)
            if (idx < nc) {
                mloc = fmaxf(mloc, e);
                if (fast && u < 4) e_buf[c0 + idx][hsel] = e;
            }
        }
    }
    // cross-group max per head (lanes with same (lane&3) hold same head)
    mloc = fmaxf(mloc, __shfl_xor(mloc, 8, 64));
    mloc = fmaxf(mloc, __shfl_xor(mloc, 16, 64));
    mloc = fmaxf(mloc, __shfl_xor(mloc, 32, 64));
    float m[HH];
    m[0] = __shfl(mloc, 0, 64);
    m[1] = __shfl(mloc, 2, 64);
    m[2] = __shfl(mloc, 1, 64);
    m[3] = __shfl(mloc, 3, 64);

    if (fast) {
        int i0 = lane, i1 = lane + 64;
        float ex0[HH] = {0.f, 0.f, 0.f, 0.f}, ex1[HH] = {0.f, 0.f, 0.f, 0.f};
        if (i0 < cnt) {
            float4 ev = *(const float4*)e_buf[i0];
            ex0[0] = __expf(ev.x - m[0]); ex0[1] = __expf(ev.y - m[1]);
            ex0[2] = __expf(ev.z - m[2]); ex0[3] = __expf(ev.w - m[3]);
        }
        if (i1 < cnt) {
            float4 ev = *(const float4*)e_buf[i1];
            ex1[0] = __expf(ev.x - m[0]); ex1[1] = __expf(ev.y - m[1]);
            ex1[2] = __expf(ev.z - m[2]); ex1[3] = __expf(ev.w - m[3]);
        }
        float rl[HH];
#pragma unroll
        for (int h = 0; h < HH; ++h) {
            float v = ex0[h] + ex1[h];
#pragma unroll
            for (int off = 1; off < 64; off <<= 1) v += __shfl_xor(v, off, 64);
            rl[h] = 1.0f / v;
        }
        if (i0 < cnt)
            out[ed[base + i0].x] = 0.25f * (ex0[0]*rl[0] + ex0[1]*rl[1] + ex0[2]*rl[2] + ex0[3]*rl[3]);
        if (i1 < cnt)
            out[ed[base + i1].x] = 0.25f * (ex1[0]*rl[0] + ex1[1]*rl[1] + ex1[2]*rl[2] + ex1[3]*rl[3]);
    } else {
        // slow path (cnt > 128): 16-lane recompute form; practically never taken
        int g = lane >> 4, t = lane & 15;
        float4 kkA[HH], kkB[HH];
        float2 qv[HH];
        const float* kkbase = kk + (size_t)s * (HH * FF) + t * 8;
        const float* qbase  = q  + (size_t)s * (HH * DD) + t * 2;
#pragma unroll
        for (int h = 0; h < HH; ++h) {
            kkA[h] = *(const float4*)(kkbase + h * FF);
            kkB[h] = *(const float4*)(kkbase + h * FF + 4);
            qv[h]  = *(const float2*)(qbase + h * DD);
        }
        float lacc[HH] = {0.f, 0.f, 0.f, 0.f};
        for (int c0 = 0; c0 < cnt; c0 += 64) {
            int nc = min(cnt - c0, 64);
            int pv = 0, dv = 0;
            if (lane < nc) { int2 pd = ed[base + c0 + lane]; pv = pd.x; dv = pd.y; }
            for (int j0 = 0; j0 < nc; j0 += 4) {
                float ev[HH]; int e_i;
                int idx = score4(rel, k, pv, dv, j0, g, t, kkA, kkB, qv, ev, &e_i);
                if (idx < nc && t == 0) {
#pragma unroll
                    for (int h = 0; h < HH; ++h) lacc[h] += __expf(ev[h] - m[h]);
                }
            }
        }
        float rl[HH];
#pragma unroll
        for (int h = 0; h < HH; ++h) {
            float v = lacc[h];
#pragma unroll
            for (int off = 1; off < 64; off <<= 1) v += __shfl_xor(v, off, 64);
            rl[h] = 1.0f / v;
        }
        for (int c0 = 0; c0 < cnt; c0 += 64) {
            int nc = min(cnt - c0, 64);
            int pv = 0, dv = 0;
            if (lane < nc) { int2 pd = ed[base + c0 + lane]; pv = pd.x; dv = pd.y; }
            for (int j0 = 0; j0 < nc; j0 += 4) {
                float ev[HH]; int e_i;
                int idx = score4(rel, k, pv, dv, j0, g, t, kkA, kkB, qv, ev, &e_i);
                if (idx < nc && t == 0) {
                    float a = __expf(ev[0]-m[0])*rl[0] + __expf(ev[1]-m[1])*rl[1]
                            + __expf(ev[2]-m[2])*rl[2] + __expf(ev[3]-m[3])*rl[3];
                    out[e_i] = 0.25f * a;
                }
            }
        }
    }
}

extern "C" void kernel_launch(void* const* d_in, const int* in_sizes, int n_in,
                              void* d_out, int out_size, void* d_ws, size_t ws_size,
                              hipStream_t stream) {
    const float* feat = (const float*)d_in[0];   // (N,1,F)
    const float* rel  = (const float*)d_in[1];   // (E,1,F)
    const int*   src  = (const int*)d_in[2];
    const int*   dst  = (const int*)d_in[3];
    const float* wq   = (const float*)d_in[4];   // (H,F,D)
    const float* wk   = (const float*)d_in[5];
    float* out = (float*)d_out;

    const int N = in_sizes[0] / FF;
    const int E = in_sizes[2];

    float* q      = (float*)d_ws;                     // N*H*D
    float* k      = q  + (size_t)N * HH * DD;         // N*H*D
    float* kk     = k  + (size_t)N * HH * DD;         // N*H*F
    int*   counts = (int*)(kk + (size_t)N * HH * FF); // N
    int*   gcur   = counts + N;                       // 1
    int*   start  = gcur + 1;                         // N
    int*   cursor = start + N;                        // N
    int2*  ed     = (int2*)(cursor + N);              // E (perm,dst)

    int nb  = (N + 255) / 256;
    int QKB = (N + 31) / 32;
    int HB  = (E + 1023) / 1024;
    int KKB = (N + 15) / 16;

    hipMemsetAsync(counts, 0, (size_t)(N + 1) * sizeof(int), stream);
    qk_hist_kernel<<<QKB + HB, 256, 0, stream>>>(feat, wq, wk, q, k, N, src, counts, E, QKB);
    kk_alloc_kernel<<<KKB + nb, 256, 0, stream>>>(k, wk, kk, N, counts, start, cursor, gcur, KKB);
    scatter_kernel<<<(E + 255) / 256, 256, 0, stream>>>(src, dst, cursor, ed, E);
    group_kernel<<<N, 64, 0, stream>>>(rel, ed, q, k, kk, start, counts, out, N);
}

// Round 10
// 419.402 us; speedup vs baseline: 1.1565x; 1.1565x over previous
//
#include <hip/hip_runtime.h>

#define HH 4
#define FF 128
#define DD 32

typedef float f32x4 __attribute__((ext_vector_type(4)));

// ---------------- scatter (sort) ----------------

__global__ void scatter_kernel(const int* __restrict__ src, const int* __restrict__ dst,
                               int* __restrict__ cursor, int2* __restrict__ ed, int E) {
    int i = blockIdx.x * blockDim.x + threadIdx.x;
    if (i >= E) return;
    int s = src[i];
    int pos = atomicAdd(&cursor[s], 1);
    long long pack = (unsigned)i | ((long long)dst[i] << 32);   // .x=i, .y=dst (LE)
    __builtin_nontemporal_store(pack, (long long*)&ed[pos]);
}

// ---------------- fused: q+k projection + histogram ----------------
// Each thread owns (h,d) and computes BOTH q and k for 16 entities
// (entity-half split): every staged fs float4 feeds 8 FMA (was 4).

__global__ __launch_bounds__(256) void qk_hist_kernel(
    const float* __restrict__ feat, const float* __restrict__ wq,
    const float* __restrict__ wk, float* __restrict__ q,
    float* __restrict__ k, int N,
    const int* __restrict__ src, int* __restrict__ counts, int E, int QKB) {
    __shared__ float fs[32 * FF];
    int bid = blockIdx.x;
    if (bid >= QKB) {           // ---- histogram role ----
        int i = ((bid - QKB) * 256 + threadIdx.x) * 4;
        if (i + 3 < E) {
            int4 v = *(const int4*)(src + i);
            atomicAdd(&counts[v.x], 1);
            atomicAdd(&counts[v.y], 1);
            atomicAdd(&counts[v.z], 1);
            atomicAdd(&counts[v.w], 1);
        } else {
            for (; i < E; ++i) atomicAdd(&counts[src[i]], 1);
        }
        return;
    }
    // ---- qk role ----
    int n0 = bid * 32;
    int nb = N - n0; if (nb > 32) nb = 32;
    const float4* s4 = (const float4*)(feat + (size_t)n0 * FF);
    int nf4 = nb * FF / 4;
    for (int i = threadIdx.x; i < nf4; i += 256) ((float4*)fs)[i] = s4[i];
    __syncthreads();

    int half = threadIdx.x >> 7;     // entity half: 0 -> e 0..15, 1 -> e 16..31
    int o    = threadIdx.x & 127;
    int h = o >> 5, d = o & 31;
    const float* wqp = wq + ((size_t)h * FF) * DD + d;
    const float* wkp = wk + ((size_t)h * FF) * DD + d;

    float accq[16], acck[16];
#pragma unroll
    for (int e = 0; e < 16; ++e) { accq[e] = 0.f; acck[e] = 0.f; }
    for (int f = 0; f < FF; f += 4) {
        float wq0 = wqp[(f + 0) * DD], wq1 = wqp[(f + 1) * DD];
        float wq2 = wqp[(f + 2) * DD], wq3 = wqp[(f + 3) * DD];
        float wk0 = wkp[(f + 0) * DD], wk1 = wkp[(f + 1) * DD];
        float wk2 = wkp[(f + 2) * DD], wk3 = wkp[(f + 3) * DD];
#pragma unroll
        for (int e = 0; e < 16; ++e) {
            float4 fv = *(const float4*)&fs[(half * 16 + e) * FF + f];
            accq[e] += fv.x * wq0 + fv.y * wq1 + fv.z * wq2 + fv.w * wq3;
            acck[e] += fv.x * wk0 + fv.y * wk1 + fv.z * wk2 + fv.w * wk3;
        }
    }
    int ecnt = nb - half * 16; if (ecnt < 0) ecnt = 0; if (ecnt > 16) ecnt = 16;
    for (int e = 0; e < ecnt; ++e) {
        size_t n = (size_t)(n0 + half * 16 + e);
        q[(n * HH + h) * DD + d] = accq[e];
        k[(n * HH + h) * DD + d] = acck[e];
    }
}

// ---------------- fused: kk projection + group-offset alloc ----------------

__global__ __launch_bounds__(256) void kk_alloc_kernel(
    const float* __restrict__ kbuf, const float* __restrict__ wk,
    float* __restrict__ kkout, int N,
    const int* __restrict__ counts, int* __restrict__ startb,
    int* __restrict__ cursor, int* __restrict__ gcur, int KKB) {
    __shared__ float ks[16 * FF];
    int bid = blockIdx.x;
    if (bid >= KKB) {           // ---- alloc role: wave scan + one atomic ----
        int sid = (bid - KKB) * 256 + threadIdx.x;
        int lane = threadIdx.x & 63;
        int cnt = (sid < N) ? counts[sid] : 0;
        int incl = cnt;
#pragma unroll
        for (int off = 1; off < 64; off <<= 1) {
            int y = __shfl_up(incl, off, 64);
            if (lane >= off) incl += y;
        }
        int total = __shfl(incl, 63, 64);
        int base = 0;
        if (lane == 63) base = atomicAdd(gcur, total);
        base = __shfl(base, 63, 64);
        if (sid < N) {
            int st = base + incl - cnt;
            startb[sid] = st;
            cursor[sid] = st;
        }
        return;
    }
    // ---- kk role ----
    int n0 = bid * 16;
    int nb = N - n0; if (nb > 16) nb = 16;
    const float4* s4 = (const float4*)(kbuf + (size_t)n0 * FF);
    int nf4 = nb * FF / 4;
    for (int i = threadIdx.x; i < nf4; i += 256) ((float4*)ks)[i] = s4[i];
    __syncthreads();

    int o = threadIdx.x;
    int h1 = o >> 7, f1 = o & 127;
    int h2 = h1 + 2;
    const float* w1 = wk + ((size_t)h1 * FF + f1) * DD;
    const float* w2 = wk + ((size_t)h2 * FF + f1) * DD;

    float acc1[16], acc2[16];
#pragma unroll
    for (int e = 0; e < 16; ++e) { acc1[e] = 0.f; acc2[e] = 0.f; }
    for (int d = 0; d < DD; d += 4) {
        float4 wv1 = *(const float4*)&w1[d];
        float4 wv2 = *(const float4*)&w2[d];
#pragma unroll
        for (int e = 0; e < 16; ++e) {
            float4 k1 = *(const float4*)&ks[e * FF + h1 * DD + d];
            float4 k2 = *(const float4*)&ks[e * FF + h2 * DD + d];
            acc1[e] += k1.x * wv1.x + k1.y * wv1.y + k1.z * wv1.z + k1.w * wv1.w;
            acc2[e] += k2.x * wv2.x + k2.y * wv2.y + k2.z * wv2.z + k2.w * wv2.w;
        }
    }
    for (int e = 0; e < nb; ++e) {
        kkout[((size_t)(n0 + e) * HH + h1) * FF + f1] = acc1[e];
        kkout[((size_t)(n0 + e) * HH + h2) * FF + f1] = acc2[e];
    }
}

// ---------------- group kernel v10: 4 srcs/block (r4 shape) + 5-shfl (r8 loop) ----

__device__ __forceinline__ int score4(         // slow-path helper (16-lane form)
    const float* __restrict__ rel, const float* __restrict__ k,
    int pv, int dv, int j0, int g, int t,
    const float4* kkA, const float4* kkB, const float2* qv,
    float* ev, int* e_i_out) {
    int idx = j0 + g;
    int e_i = __shfl(pv, idx, 64);
    int dd  = __shfl(dv, idx, 64);
    *e_i_out = e_i;
    const float* rp = rel + (size_t)e_i * FF + t * 8;
    f32x4 r0 = __builtin_nontemporal_load((const f32x4*)rp);
    f32x4 r1 = __builtin_nontemporal_load((const f32x4*)(rp + 4));
#pragma unroll
    for (int h = 0; h < HH; ++h) {
        float2 kv = *(const float2*)(k + ((size_t)dd * HH + h) * DD + t * 2);
        float a = r0.x * kkA[h].x + r0.y * kkA[h].y + r0.z * kkA[h].z + r0.w * kkA[h].w
                + r1.x * kkB[h].x + r1.y * kkB[h].y + r1.z * kkB[h].z + r1.w * kkB[h].w
                + qv[h].x * kv.x + qv[h].y * kv.y;
#pragma unroll
        for (int off = 1; off < 16; off <<= 1) a += __shfl_xor(a, off, 64);
        ev[h] = a >= 0.f ? a : 0.01f * a;
    }
    return idx;
}

__global__ __launch_bounds__(256) void group_kernel(
    const float* __restrict__ rel, const int2* __restrict__ ed,
    const float* __restrict__ q, const float* __restrict__ k,
    const float* __restrict__ kk, const int* __restrict__ start,
    const int* __restrict__ counts, float* __restrict__ out, int N) {
    __shared__ __align__(16) float e_buf_all[4][128][4];
    int wid = threadIdx.x >> 6;
    int s = blockIdx.x * 4 + wid;
    if (s >= N) return;
    int cnt = counts[s];
    if (cnt == 0) return;
    int base = start[s];
    int lane = threadIdx.x & 63;
    int g = lane >> 4, t = lane & 15;
    int hsel = ((t & 1) << 1) | ((t & 2) >> 1);
    float (*e_buf)[4] = e_buf_all[wid];

    float4 kkA[HH], kkB[HH];
    float2 qv[HH];
    const float* kkbase = kk + (size_t)s * (HH * FF) + t * 8;
    const float* qbase  = q  + (size_t)s * (HH * DD) + t * 2;
#pragma unroll
    for (int h = 0; h < HH; ++h) {
        kkA[h] = *(const float4*)(kkbase + h * FF);
        kkB[h] = *(const float4*)(kkbase + h * FF + 4);
        qv[h]  = *(const float2*)(qbase + h * DD);
    }

    float mloc = -INFINITY;
    bool fast = (cnt <= 128);

    for (int c0 = 0; c0 < cnt; c0 += 64) {
        int nc = min(cnt - c0, 64);
        int pv = 0, dv = 0;
        if (lane < nc) { int2 pd = ed[base + c0 + lane]; pv = pd.x; dv = pd.y; }
        for (int j0 = 0; j0 < nc; j0 += 4) {
            int idx = j0 + g;
            int sel = idx < nc ? idx : 0;
            int e_i = __shfl(pv, sel, 64);
            int dd  = __shfl(dv, sel, 64);
            const float* rp = rel + (size_t)e_i * FF + t * 8;
            f32x4 r0 = __builtin_nontemporal_load((const f32x4*)rp);
            f32x4 r1 = __builtin_nontemporal_load((const f32x4*)(rp + 4));
            float p[HH];
#pragma unroll
            for (int h = 0; h < HH; ++h) {
                float2 kv = *(const float2*)(k + ((size_t)dd * HH + h) * DD + t * 2);
                p[h] = r0.x * kkA[h].x + r0.y * kkA[h].y + r0.z * kkA[h].z + r0.w * kkA[h].w
                     + r1.x * kkB[h].x + r1.y * kkB[h].y + r1.z * kkB[h].z + r1.w * kkB[h].w
                     + qv[h].x * kv.x + qv[h].y * kv.y;
            }
            // 5-shfl multi-head butterfly (r8, verified)
            float sx = (t & 1) ? p[0] : p[2];
            float sy = (t & 1) ? p[1] : p[3];
            float rx = __shfl_xor(sx, 1, 64);
            float ry = __shfl_xor(sy, 1, 64);
            float a0 = ((t & 1) ? p[2] : p[0]) + rx;
            float a1 = ((t & 1) ? p[3] : p[1]) + ry;
            float sz = (t & 2) ? a0 : a1;
            float rz = __shfl_xor(sz, 2, 64);
            float e = ((t & 2) ? a1 : a0) + rz;
            e += __shfl_xor(e, 4, 64);
            e += __shfl_xor(e, 8, 64);
            e = e >= 0.f ? e : 0.01f * e;              // leaky_relu(0.01)
            if (idx < nc) {
                mloc = fmaxf(mloc, e);
                if (fast && t < 4) e_buf[c0 + idx][hsel] = e;
            }
        }
    }
    mloc = fmaxf(mloc, __shfl_xor(mloc, 16, 64));
    mloc = fmaxf(mloc, __shfl_xor(mloc, 32, 64));
    float m[HH];
    m[0] = __shfl(mloc, 0, 64);
    m[1] = __shfl(mloc, 2, 64);
    m[2] = __shfl(mloc, 1, 64);
    m[3] = __shfl(mloc, 3, 64);

    if (fast) {
        int i0 = lane, i1 = lane + 64;
        float ex0[HH] = {0.f, 0.f, 0.f, 0.f}, ex1[HH] = {0.f, 0.f, 0.f, 0.f};
        if (i0 < cnt) {
            float4 ev = *(const float4*)e_buf[i0];
            ex0[0] = __expf(ev.x - m[0]); ex0[1] = __expf(ev.y - m[1]);
            ex0[2] = __expf(ev.z - m[2]); ex0[3] = __expf(ev.w - m[3]);
        }
        if (i1 < cnt) {
            float4 ev = *(const float4*)e_buf[i1];
            ex1[0] = __expf(ev.x - m[0]); ex1[1] = __expf(ev.y - m[1]);
            ex1[2] = __expf(ev.z - m[2]); ex1[3] = __expf(ev.w - m[3]);
        }
        float rl[HH];
#pragma unroll
        for (int h = 0; h < HH; ++h) {
            float v = ex0[h] + ex1[h];
#pragma unroll
            for (int off = 1; off < 64; off <<= 1) v += __shfl_xor(v, off, 64);
            rl[h] = 1.0f / v;
        }
        if (i0 < cnt)
            out[ed[base + i0].x] = 0.25f * (ex0[0]*rl[0] + ex0[1]*rl[1] + ex0[2]*rl[2] + ex0[3]*rl[3]);
        if (i1 < cnt)
            out[ed[base + i1].x] = 0.25f * (ex1[0]*rl[0] + ex1[1]*rl[1] + ex1[2]*rl[2] + ex1[3]*rl[3]);
    } else {
        // slow path (cnt > 128): recompute; practically never taken
        float lacc[HH] = {0.f, 0.f, 0.f, 0.f};
        for (int c0 = 0; c0 < cnt; c0 += 64) {
            int nc = min(cnt - c0, 64);
            int pv = 0, dv = 0;
            if (lane < nc) { int2 pd = ed[base + c0 + lane]; pv = pd.x; dv = pd.y; }
            for (int j0 = 0; j0 < nc; j0 += 4) {
                float ev[HH]; int e_i;
                int idx = score4(rel, k, pv, dv, j0, g, t, kkA, kkB, qv, ev, &e_i);
                if (idx < nc && t == 0) {
#pragma unroll
                    for (int h = 0; h < HH; ++h) lacc[h] += __expf(ev[h] - m[h]);
                }
            }
        }
        float rl[HH];
#pragma unroll
        for (int h = 0; h < HH; ++h) {
            float v = lacc[h];
#pragma unroll
            for (int off = 1; off < 64; off <<= 1) v += __shfl_xor(v, off, 64);
            rl[h] = 1.0f / v;
        }
        for (int c0 = 0; c0 < cnt; c0 += 64) {
            int nc = min(cnt - c0, 64);
            int pv = 0, dv = 0;
            if (lane < nc) { int2 pd = ed[base + c0 + lane]; pv = pd.x; dv = pd.y; }
            for (int j0 = 0; j0 < nc; j0 += 4) {
                float ev[HH]; int e_i;
                int idx = score4(rel, k, pv, dv, j0, g, t, kkA, kkB, qv, ev, &e_i);
                if (idx < nc && t == 0) {
                    float a = __expf(ev[0]-m[0])*rl[0] + __expf(ev[1]-m[1])*rl[1]
                            + __expf(ev[2]-m[2])*rl[2] + __expf(ev[3]-m[3])*rl[3];
                    out[e_i] = 0.25f * a;
                }
            }
        }
    }
}

extern "C" void kernel_launch(void* const* d_in, const int* in_sizes, int n_in,
                              void* d_out, int out_size, void* d_ws, size_t ws_size,
                              hipStream_t stream) {
    const float* feat = (const float*)d_in[0];   // (N,1,F)
    const float* rel  = (const float*)d_in[1];   // (E,1,F)
    const int*   src  = (const int*)d_in[2];
    const int*   dst  = (const int*)d_in[3];
    const float* wq   = (const float*)d_in[4];   // (H,F,D)
    const float* wk   = (const float*)d_in[5];
    float* out = (float*)d_out;

    const int N = in_sizes[0] / FF;
    const int E = in_sizes[2];

    float* q      = (float*)d_ws;                     // N*H*D
    float* k      = q  + (size_t)N * HH * DD;         // N*H*D
    float* kk     = k  + (size_t)N * HH * DD;         // N*H*F
    int*   counts = (int*)(kk + (size_t)N * HH * FF); // N
    int*   gcur   = counts + N;                       // 1
    int*   start  = gcur + 1;                         // N
    int*   cursor = start + N;                        // N
    int2*  ed     = (int2*)(cursor + N);              // E (perm,dst)

    int nb  = (N + 255) / 256;
    int QKB = (N + 31) / 32;
    int HB  = (E + 1023) / 1024;
    int KKB = (N + 15) / 16;

    hipMemsetAsync(counts, 0, (size_t)(N + 1) * sizeof(int), stream);
    qk_hist_kernel<<<QKB + HB, 256, 0, stream>>>(feat, wq, wk, q, k, N, src, counts, E, QKB);
    kk_alloc_kernel<<<KKB + nb, 256, 0, stream>>>(k, wk, kk, N, counts, start, cursor, gcur, KKB);
    scatter_kernel<<<(E + 255) / 256, 256, 0, stream>>>(src, dst, cursor, ed, E);
    group_kernel<<<(N + 3) / 4, 256, 0, stream>>>(rel, ed, q, k, kk, start, counts, out, N);
}